// Round 7
// baseline (2122.781 us; speedup 1.0000x reference)
//
#include <hip/hip_runtime.h>
#include <math.h>

#define NC 4096
#define OVCAP 131072
#define SL 4   // slices per sub-bucket in reduction kernels

// Real XCD id: s_getreg(HW_REG_XCC_ID=20, offset 0, size 4) [verified working r6]
__device__ __forceinline__ int xcd_id() {
    return (int)__builtin_amdgcn_s_getreg(20 | (0 << 6) | ((4 - 1) << 11));
}

// ============================ FAST PATH ==========================================
// Level 1: scatter to 64 buckets x 8 XCD shards (line completes in ~100ns -> one
// full-line writeback). Level 2: register-routed per-bucket reductions (lane =
// cluster-in-bucket), no hot-loop atomics.

__global__ __launch_bounds__(256) void k_bucket(const float* __restrict__ data,
                                                const int* __restrict__ ids,
                                                float4* __restrict__ P1,
                                                int* __restrict__ cnt,
                                                float4* __restrict__ ov,
                                                int* __restrict__ novf,
                                                float* __restrict__ gmom,
                                                int n, int CAP1) {
    __shared__ float st[256 * 5];
    int xcd = xcd_id() & 7;
    int ntiles = (n + 255) / 256;
    for (int t = blockIdx.x; t < ntiles; t += gridDim.x) {
        int vbase = t * 256;
        int fbase = vbase * 5;
        int nf = min(256 * 5, n * 5 - fbase);
        for (int j = threadIdx.x; j < nf; j += 256) st[j] = data[fbase + j];
        __syncthreads();
        int v = vbase + threadIdx.x;
        if (v < n) {
            int l = threadIdx.x * 5;
            float x = st[l], y = st[l + 1], z = st[l + 2];
            int id = ids[v];
            int sub = ((id >> 6) << 3) + xcd;     // bucket-major, XCD shard
            int pos = atomicAdd(&cnt[sub], 1);
            if (pos < CAP1) {
                P1[(size_t)sub * CAP1 + pos] = make_float4(x, y, z, __int_as_float(id));
            } else {
                // ~impossible overflow (CAP1 = mean + 45 sigma); exact handling
                int ovi = atomicAdd(novf, 1);
                if (ovi < OVCAP) ov[ovi] = make_float4(x, y, z, __int_as_float(id));
                atomicAdd(&gmom[0 * NC + id], 1.0f);
                atomicAdd(&gmom[1 * NC + id], x);
                atomicAdd(&gmom[2 * NC + id], y);
                atomicAdd(&gmom[3 * NC + id], z);
                atomicAdd(&gmom[4 * NC + id], x * x);
                atomicAdd(&gmom[5 * NC + id], x * y);
                atomicAdd(&gmom[6 * NC + id], x * z);
                atomicAdd(&gmom[7 * NC + id], y * y);
                atomicAdd(&gmom[8 * NC + id], y * z);
                atomicAdd(&gmom[9 * NC + id], z * z);
            }
        }
        __syncthreads();
    }
}

// ---------------- k_moments: register-routed 10-moment accumulation -------------
// grid = 512 * SL blocks; block handles slice q of sub-bucket sub.
// Each wave: lane owns cluster (bucket*64 + lane); stage 64 voxels, broadcast
// each via uniform-address LDS read, owner lane accumulates in VGPRs.
__global__ __launch_bounds__(256) void k_moments(const float4* __restrict__ P1,
                                                 const int* __restrict__ cnt,
                                                 float* __restrict__ gmom,
                                                 int CAP1) {
    __shared__ float4 stg[256];
    __shared__ float part[4][64][10];
    int sub = blockIdx.x / SL;
    int q   = blockIdx.x % SL;
    int bucket = sub >> 3;
    int m = min(cnt[sub], CAP1);
    int start = (int)((long long)m * q / SL);
    int end   = (int)((long long)m * (q + 1) / SL);
    size_t base = (size_t)sub * CAP1;
    int tid = threadIdx.x, w = tid >> 6, lane = tid & 63;

    float a[10];
#pragma unroll
    for (int k = 0; k < 10; k++) a[k] = 0.0f;

    int iters = (end - start + 255) / 256;   // uniform across block
    for (int it = 0; it < iters; it++) {
        int b = start + it * 256 + w * 64;
        int c64 = end - b;
        c64 = c64 < 0 ? 0 : (c64 > 64 ? 64 : c64);
        if (lane < c64) stg[tid] = P1[base + b + lane];
        __syncthreads();                      // orders stage before broadcast reads
        for (int j = 0; j < c64; j++) {
            float4 d = stg[w * 64 + j];       // uniform addr -> LDS broadcast
            int id = __float_as_int(d.w);
            if ((id & 63) == lane) {
                a[0] += 1.0f;
                a[1] += d.x; a[2] += d.y; a[3] += d.z;
                a[4] += d.x * d.x; a[5] += d.x * d.y; a[6] += d.x * d.z;
                a[7] += d.y * d.y; a[8] += d.y * d.z; a[9] += d.z * d.z;
            }
        }
        __syncthreads();                      // protect stg before next stage
    }
#pragma unroll
    for (int k = 0; k < 10; k++) part[w][lane][k] = a[k];
    __syncthreads();
    if (tid < 64) {
        int c = bucket * 64 + tid;
#pragma unroll
        for (int k = 0; k < 10; k++) {
            float s = part[0][tid][k] + part[1][tid][k] + part[2][tid][k] + part[3][tid][k];
            if (s != 0.0f) atomicAdd(&gmom[k * NC + c], s);
        }
    }
}

// ---------------- k_eigen: per-cluster eigensolve + B/center/count --------------
// pc[c] = {cx, cy, cz, dirwt}; pv[c] = {vx, vy, vz, cnt}
__global__ void k_eigen(const float* __restrict__ gmom, float* __restrict__ out,
                        float4* __restrict__ pc, float4* __restrict__ pv) {
    int c = blockIdx.x * blockDim.x + threadIdx.x;
    if (c >= NC) return;

    float cnt = gmom[0 * NC + c];
    float sx  = gmom[1 * NC + c], sy  = gmom[2 * NC + c], sz  = gmom[3 * NC + c];
    float sxx = gmom[4 * NC + c], sxy = gmom[5 * NC + c], sxz = gmom[6 * NC + c];
    float syy = gmom[7 * NC + c], syz = gmom[8 * NC + c], szz = gmom[9 * NC + c];

    double dn  = (double)cnt;
    double inv = 1.0 / fmax(dn, 1.0);
    double cx = sx * inv, cy = sy * inv, cz = sz * inv;

    double a00 = (double)sxx - dn * cx * cx;
    double a01 = (double)sxy - dn * cx * cy;
    double a02 = (double)sxz - dn * cx * cz;
    double a11 = (double)syy - dn * cy * cy;
    double a12 = (double)syz - dn * cy * cz;
    double a22 = (double)szz - dn * cz * cz;

    // Smith's trigonometric eigenvalues
    double q  = (a00 + a11 + a22) / 3.0;
    double p1 = a01 * a01 + a02 * a02 + a12 * a12;
    double b00 = a00 - q, b11 = a11 - q, b22 = a22 - q;
    double p2 = b00 * b00 + b11 * b11 + b22 * b22 + 2.0 * p1;
    double w0, w1, w2;
    if (!(p2 > 0.0)) {
        w0 = w1 = w2 = q;
    } else {
        double p  = sqrt(p2 / 6.0);
        double ip = 1.0 / p;
        double c00 = b00 * ip, c01 = a01 * ip, c02 = a02 * ip;
        double c11 = b11 * ip, c12 = a12 * ip, c22 = b22 * ip;
        double detB = c00 * (c11 * c22 - c12 * c12)
                    - c01 * (c01 * c22 - c12 * c02)
                    + c02 * (c01 * c12 - c11 * c02);
        double r = fmin(1.0, fmax(-1.0, detB * 0.5));
        double phi = acos(r) / 3.0;
        w2 = q + 2.0 * p * cos(phi);
        w0 = q + 2.0 * p * cos(phi + 2.0943951023931953);
        w1 = 3.0 * q - w2 - w0;
    }

    double denom = (w2 == 0.0) ? 1.0 : w2;
    double dirwt = (w2 == 0.0) ? 0.0 : (1.0 - w1 / w2);

    // eigenvector of w2 via (A - w1 I)(A - w0 I)
    double C00 = a00 - w1, C11 = a11 - w1, C22 = a22 - w1;
    double D00 = a00 - w0, D11 = a11 - w0, D22 = a22 - w0;
    double M00 = C00 * D00 + a01 * a01 + a02 * a02;
    double M10 = a01 * D00 + C11 * a01 + a12 * a02;
    double M20 = a02 * D00 + a12 * a01 + C22 * a02;
    double M01 = C00 * a01 + a01 * D11 + a02 * a12;
    double M11 = a01 * a01 + C11 * D11 + a12 * a12;
    double M21 = a02 * a01 + a12 * D11 + C22 * a12;
    double M02 = C00 * a02 + a01 * a12 + a02 * D22;
    double M12 = a01 * a02 + C11 * a12 + a12 * D22;
    double M22 = a02 * a02 + a12 * a12 + C22 * D22;
    double n0 = M00 * M00 + M10 * M10 + M20 * M20;
    double n1 = M01 * M01 + M11 * M11 + M21 * M21;
    double n2 = M02 * M02 + M12 * M12 + M22 * M22;
    double vx, vy, vz, nn;
    if (n0 >= n1 && n0 >= n2) { vx = M00; vy = M10; vz = M20; nn = n0; }
    else if (n1 >= n2)        { vx = M01; vy = M11; vz = M21; nn = n1; }
    else                      { vx = M02; vy = M12; vz = M22; nn = n2; }
    if (nn > 1e-300) {
        double rn = 1.0 / sqrt(nn);
        vx *= rn; vy *= rn; vz *= rn;
    } else {
        vx = vy = vz = 0.0;
    }

    bool small = cnt < 2.0f;
    float bscale = small ? 0.0f : (float)(1.0 / denom);

    float* o = out + c * 16;
    o[0]  = (float)cx;
    o[1]  = (float)cy;
    o[2]  = (float)cz;
    o[3]  = (float)a00 * bscale;
    o[4]  = (float)a01 * bscale;
    o[5]  = (float)a02 * bscale;
    o[6]  = (float)a01 * bscale;
    o[7]  = (float)a11 * bscale;
    o[8]  = (float)a12 * bscale;
    o[9]  = (float)a02 * bscale;
    o[10] = (float)a12 * bscale;
    o[11] = (float)a22 * bscale;
    o[15] = cnt;

    pc[c] = make_float4((float)cx, (float)cy, (float)cz, (float)dirwt);
    pv[c] = make_float4((float)vx, (float)vy, (float)vz, cnt);
}

// ---------------- k_sc2: sc reduction over bucketed data ------------------------
__global__ __launch_bounds__(256) void k_sc2(const float4* __restrict__ P1,
                                             const int* __restrict__ cnt,
                                             const float4* __restrict__ pc,
                                             const float4* __restrict__ pv,
                                             float* __restrict__ gsc, int CAP1) {
    __shared__ float ssc[64];
    int sub = blockIdx.x / SL;
    int q   = blockIdx.x % SL;
    int bucket = sub >> 3;
    int m = min(cnt[sub], CAP1);
    int start = (int)((long long)m * q / SL);
    int end   = (int)((long long)m * (q + 1) / SL);
    size_t base = (size_t)sub * CAP1;
    int tid = threadIdx.x;
    if (tid < 64) ssc[tid] = 0.0f;
    __syncthreads();
    for (int i = start + tid; i < end; i += 256) {
        float4 d = P1[base + i];
        int id = __float_as_int(d.w);
        float4 c4 = pc[id];
        float4 v4 = pv[id];
        float xc = d.x - c4.x, yc = d.y - c4.y, zc = d.z - c4.z;
        float x0 = xc * v4.x + yc * v4.y + zc * v4.z;
        float px = xc - x0 * v4.x;
        float py = yc - x0 * v4.y;
        float pz = zc - x0 * v4.z;
        atomicAdd(&ssc[id & 63], x0 * sqrtf(px * px + py * py + pz * pz));
    }
    __syncthreads();
    if (tid < 64) {
        float v = ssc[tid];
        if (v != 0.0f) atomicAdd(&gsc[bucket * 64 + tid], v);
    }
}

// ---------------- k_final2: overflow sc + v0 finalize ---------------------------
__global__ void k_final2(const float4* __restrict__ pc, const float4* __restrict__ pv,
                         const float* __restrict__ gsc,
                         const float4* __restrict__ ov, const int* __restrict__ novf,
                         float* __restrict__ out) {
    int c = blockIdx.x * blockDim.x + threadIdx.x;
    if (c >= NC) return;
    float4 c4 = pc[c];
    float4 v4 = pv[c];
    float tot = gsc[c];
    int m = min(*novf, OVCAP);     // normally 0
    for (int i = 0; i < m; i++) {
        float4 d = ov[i];
        if (__float_as_int(d.w) == c) {
            float xc = d.x - c4.x, yc = d.y - c4.y, zc = d.z - c4.z;
            float x0 = xc * v4.x + yc * v4.y + zc * v4.z;
            float px = xc - x0 * v4.x;
            float py = yc - x0 * v4.y;
            float pz = zc - x0 * v4.z;
            tot += x0 * sqrtf(px * px + py * py + pz * pz);
        }
    }
    float s = (tot < 0.0f) ? -c4.w : c4.w;
    if (v4.w < 2.0f) s = 0.0f;
    out[c * 16 + 12] = v4.x * s;
    out[c * 16 + 13] = v4.y * s;
    out[c * 16 + 14] = v4.z * s;
}

// ============================ FALLBACK (r1 structure) ============================
__global__ __launch_bounds__(1024) void k_accum_raw(const float* __restrict__ data,
                                                    const int* __restrict__ ids,
                                                    float* __restrict__ gmom, int n) {
    extern __shared__ float s[];
    for (int i = threadIdx.x; i < 10 * NC; i += blockDim.x) s[i] = 0.0f;
    __syncthreads();
    int stride = gridDim.x * blockDim.x;
    for (int i = blockIdx.x * blockDim.x + threadIdx.x; i < n; i += stride) {
        int id = ids[i];
        float x = data[i * 5 + 0], y = data[i * 5 + 1], z = data[i * 5 + 2];
        atomicAdd(&s[0 * NC + id], 1.0f);
        atomicAdd(&s[1 * NC + id], x);
        atomicAdd(&s[2 * NC + id], y);
        atomicAdd(&s[3 * NC + id], z);
        atomicAdd(&s[4 * NC + id], x * x);
        atomicAdd(&s[5 * NC + id], x * y);
        atomicAdd(&s[6 * NC + id], x * z);
        atomicAdd(&s[7 * NC + id], y * y);
        atomicAdd(&s[8 * NC + id], y * z);
        atomicAdd(&s[9 * NC + id], z * z);
    }
    __syncthreads();
    for (int i = threadIdx.x; i < 10 * NC; i += blockDim.x) {
        float v = s[i];
        if (v != 0.0f) atomicAdd(&gmom[i], v);
    }
}

__global__ __launch_bounds__(1024) void k_sc_raw(const float* __restrict__ data,
                                                 const int* __restrict__ ids,
                                                 const float4* __restrict__ pc,
                                                 const float4* __restrict__ pv,
                                                 float* __restrict__ gsc, int n) {
    extern __shared__ float4 sl4[];
    float4* spc = sl4;
    float4* spv = sl4 + NC;
    float*  ssc = (float*)(sl4 + 2 * NC);
    for (int i = threadIdx.x; i < NC; i += blockDim.x) {
        spc[i] = pc[i]; spv[i] = pv[i]; ssc[i] = 0.0f;
    }
    __syncthreads();
    int stride = gridDim.x * blockDim.x;
    for (int i = blockIdx.x * blockDim.x + threadIdx.x; i < n; i += stride) {
        int id = ids[i];
        float4 c4 = spc[id];
        float4 v4 = spv[id];
        float xc = data[i * 5 + 0] - c4.x;
        float yc = data[i * 5 + 1] - c4.y;
        float zc = data[i * 5 + 2] - c4.z;
        float x0 = xc * v4.x + yc * v4.y + zc * v4.z;
        float px = xc - x0 * v4.x;
        float py = yc - x0 * v4.y;
        float pz = zc - x0 * v4.z;
        atomicAdd(&ssc[id], x0 * sqrtf(px * px + py * py + pz * pz));
    }
    __syncthreads();
    for (int i = threadIdx.x; i < NC; i += blockDim.x) {
        float v = ssc[i];
        if (v != 0.0f) atomicAdd(&gsc[i], v);
    }
}

__global__ void k_final_fb(const float4* __restrict__ pc, const float4* __restrict__ pv,
                           const float* __restrict__ gsc, float* __restrict__ out) {
    int c = blockIdx.x * blockDim.x + threadIdx.x;
    if (c >= NC) return;
    float4 c4 = pc[c];
    float4 v4 = pv[c];
    float s = (gsc[c] < 0.0f) ? -c4.w : c4.w;
    if (v4.w < 2.0f) s = 0.0f;
    out[c * 16 + 12] = v4.x * s;
    out[c * 16 + 13] = v4.y * s;
    out[c * 16 + 14] = v4.z * s;
}

// =================================================================================
extern "C" void kernel_launch(void* const* d_in, const int* in_sizes, int n_in,
                              void* d_out, int out_size, void* d_ws, size_t ws_size,
                              hipStream_t stream) {
    const float* data = (const float*)d_in[0];
    const int*   ids  = (const int*)d_in[1];
    float* out = (float*)d_out;
    int n = in_sizes[1];

    char* ws = (char*)d_ws;
    // layout (bytes):
    //   gmom : 40960 f    @ 0        (163840)
    //   gsc  : 4096 f     @ 163840   (16384)
    //   cnt  : 512 i      @ 180224   (131072 region reserved)
    //   novf : 1 i        @ 311296   (pad -> 311552)
    //   pc   : 4096 f4    @ 311552   (65536)
    //   pv   : 4096 f4    @ 377088   (65536)
    //   ov   : 131072 f4  @ 442624   (2097152)
    //   P1   : float4     @ 2539776  (512 * CAP1 * 16)
    float*  gmom = (float*)(ws);
    float*  gsc  = (float*)(ws + 163840);
    int*    cnt  = (int*)(ws + 180224);
    int*    novf = (int*)(ws + 311296);
    float4* pc   = (float4*)(ws + 311552);
    float4* pv   = (float4*)(ws + 377088);
    float4* ov   = (float4*)(ws + 442624);
    float4* P1   = (float4*)(ws + 2539776);
    const size_t base = 2539776;

    const int CAP1 = 11776;  // mean 7813/sub-bucket; +45 sigma headroom; need = proven ws
    size_t need = base + (size_t)512 * CAP1 * 16;   // = 99,008,768 (proven available)

    if (ws_size >= need) {
        hipMemsetAsync(ws, 0, 311552, stream);  // gmom+gsc+cnt+novf
        hipLaunchKernelGGL(k_bucket, dim3(4096), dim3(256), 0, stream,
                           data, ids, P1, cnt, ov, novf, gmom, n, CAP1);
        hipLaunchKernelGGL(k_moments, dim3(512 * SL), dim3(256), 0, stream,
                           P1, cnt, gmom, CAP1);
        hipLaunchKernelGGL(k_eigen, dim3(16), dim3(256), 0, stream, gmom, out, pc, pv);
        hipLaunchKernelGGL(k_sc2, dim3(512 * SL), dim3(256), 0, stream,
                           P1, cnt, pc, pv, gsc, CAP1);
        hipLaunchKernelGGL(k_final2, dim3(16), dim3(256), 0, stream,
                           pc, pv, gsc, ov, novf, out);
    } else {
        hipMemsetAsync(ws, 0, 180224, stream);
        hipLaunchKernelGGL(k_accum_raw, dim3(256), dim3(1024), 10 * NC * 4, stream,
                           data, ids, gmom, n);
        hipLaunchKernelGGL(k_eigen, dim3(16), dim3(256), 0, stream, gmom, out, pc, pv);
        hipLaunchKernelGGL(k_sc_raw, dim3(256), dim3(1024), 2 * NC * 16 + NC * 4, stream,
                           data, ids, pc, pv, gsc, n);
        hipLaunchKernelGGL(k_final_fb, dim3(16), dim3(256), 0, stream, pc, pv, gsc, out);
    }
}

// Round 8
// 404.503 us; speedup vs baseline: 5.2479x; 5.2479x over previous
//
#include <hip/hip_runtime.h>
#include <math.h>

#define NC 4096
#define OVCAP 131072
#define SL 2            // slices per sub-bucket in reduce kernels
#define CAP1 11424      // per-sub-bucket capacity (mean 7813, +40 sigma)

// Real XCD id: s_getreg(HW_REG_XCC_ID=20, offset 0, size 4) [verified r6]
__device__ __forceinline__ int xcd_id() {
    return (int)__builtin_amdgcn_s_getreg(20 | (0 << 6) | ((4 - 1) << 11));
}

// ---------------- shared per-cluster eigensolve --------------------------------
__device__ __forceinline__ void solve_cluster(const float mom[10], float* o,
                                              float4* pcv, float4* pvv) {
    float cntf = mom[0];
    double dn  = (double)cntf;
    double inv = 1.0 / fmax(dn, 1.0);
    double cx = mom[1] * inv, cy = mom[2] * inv, cz = mom[3] * inv;

    double a00 = (double)mom[4] - dn * cx * cx;
    double a01 = (double)mom[5] - dn * cx * cy;
    double a02 = (double)mom[6] - dn * cx * cz;
    double a11 = (double)mom[7] - dn * cy * cy;
    double a12 = (double)mom[8] - dn * cy * cz;
    double a22 = (double)mom[9] - dn * cz * cz;

    double q  = (a00 + a11 + a22) / 3.0;
    double p1 = a01 * a01 + a02 * a02 + a12 * a12;
    double b00 = a00 - q, b11 = a11 - q, b22 = a22 - q;
    double p2 = b00 * b00 + b11 * b11 + b22 * b22 + 2.0 * p1;
    double w0, w1, w2;
    if (!(p2 > 0.0)) {
        w0 = w1 = w2 = q;
    } else {
        double p  = sqrt(p2 / 6.0);
        double ip = 1.0 / p;
        double c00 = b00 * ip, c01 = a01 * ip, c02 = a02 * ip;
        double c11 = b11 * ip, c12 = a12 * ip, c22 = b22 * ip;
        double detB = c00 * (c11 * c22 - c12 * c12)
                    - c01 * (c01 * c22 - c12 * c02)
                    + c02 * (c01 * c12 - c11 * c02);
        double r = fmin(1.0, fmax(-1.0, detB * 0.5));
        double phi = acos(r) / 3.0;
        w2 = q + 2.0 * p * cos(phi);
        w0 = q + 2.0 * p * cos(phi + 2.0943951023931953);
        w1 = 3.0 * q - w2 - w0;
    }

    double denom = (w2 == 0.0) ? 1.0 : w2;
    double dirwt = (w2 == 0.0) ? 0.0 : (1.0 - w1 / w2);

    double C00 = a00 - w1, C11 = a11 - w1, C22 = a22 - w1;
    double D00 = a00 - w0, D11 = a11 - w0, D22 = a22 - w0;
    double M00 = C00 * D00 + a01 * a01 + a02 * a02;
    double M10 = a01 * D00 + C11 * a01 + a12 * a02;
    double M20 = a02 * D00 + a12 * a01 + C22 * a02;
    double M01 = C00 * a01 + a01 * D11 + a02 * a12;
    double M11 = a01 * a01 + C11 * D11 + a12 * a12;
    double M21 = a02 * a01 + a12 * D11 + C22 * a12;
    double M02 = C00 * a02 + a01 * a12 + a02 * D22;
    double M12 = a01 * a02 + C11 * a12 + a12 * D22;
    double M22 = a02 * a02 + a12 * a12 + C22 * D22;
    double n0 = M00 * M00 + M10 * M10 + M20 * M20;
    double n1 = M01 * M01 + M11 * M11 + M21 * M21;
    double n2 = M02 * M02 + M12 * M12 + M22 * M22;
    double vx, vy, vz, nn;
    if (n0 >= n1 && n0 >= n2) { vx = M00; vy = M10; vz = M20; nn = n0; }
    else if (n1 >= n2)        { vx = M01; vy = M11; vz = M21; nn = n1; }
    else                      { vx = M02; vy = M12; vz = M22; nn = n2; }
    if (nn > 1e-300) {
        double rn = 1.0 / sqrt(nn);
        vx *= rn; vy *= rn; vz *= rn;
    } else {
        vx = vy = vz = 0.0;
    }

    bool small = cntf < 2.0f;
    float bscale = small ? 0.0f : (float)(1.0 / denom);

    o[0]  = (float)cx;
    o[1]  = (float)cy;
    o[2]  = (float)cz;
    o[3]  = (float)a00 * bscale;
    o[4]  = (float)a01 * bscale;
    o[5]  = (float)a02 * bscale;
    o[6]  = (float)a01 * bscale;
    o[7]  = (float)a11 * bscale;
    o[8]  = (float)a12 * bscale;
    o[9]  = (float)a02 * bscale;
    o[10] = (float)a12 * bscale;
    o[11] = (float)a22 * bscale;
    o[15] = cntf;

    *pcv = make_float4((float)cx, (float)cy, (float)cz, (float)dirwt);
    *pvv = make_float4((float)vx, (float)vy, (float)vz, cntf);
}

// ============================ FAST PATH ==========================================
// k_part: block-local 64-bucket sort + block-aggregated reservation + COALESCED
// scatter (1 LDS atomic/voxel; 64 padded global atomics per 2048-voxel tile).
__global__ __launch_bounds__(256) void k_part(const float* __restrict__ data,
                                              const int* __restrict__ ids,
                                              float4* __restrict__ P1,
                                              int* __restrict__ cnt,
                                              float4* __restrict__ ov,
                                              int* __restrict__ novf,
                                              float* __restrict__ gmom,
                                              int n) {
    __shared__ float st[256 * 5];
    __shared__ float4 srt[2048];
    __shared__ int h64[64], boff[64], bglob[64];
    int tid = threadIdx.x;
    int lane = tid & 63;
    int xcd = xcd_id() & 7;
    int ntiles = (n + 2047) >> 11;
    float vx[8], vy[8], vz[8];
    int vid[8], vrk[8];

    for (int t = blockIdx.x; t < ntiles; t += gridDim.x) {
        if (tid < 64) h64[tid] = 0;
        __syncthreads();
        for (int s = 0; s < 8; s++) {
            int vbase = (t << 11) + (s << 8);
            int nf = (n - vbase) * 5;
            nf = nf < 0 ? 0 : (nf > 1280 ? 1280 : nf);
            int fbase = vbase * 5;
            for (int j = tid; j < nf; j += 256) st[j] = data[fbase + j];
            __syncthreads();
            int v = vbase + tid;
            if (v < n) {
                int l = tid * 5;
                vx[s] = st[l]; vy[s] = st[l + 1]; vz[s] = st[l + 2];
                int id = ids[v];
                vid[s] = id;
                vrk[s] = atomicAdd(&h64[id >> 6], 1);
            } else vid[s] = -1;
            __syncthreads();
        }
        if (tid < 64) {
            int c0 = h64[tid];
            int sc = c0;
            for (int off = 1; off < 64; off <<= 1) {
                int u = __shfl_up(sc, off);
                if (lane >= off) sc += u;
            }
            boff[tid] = sc - c0;
            bglob[tid] = atomicAdd(&cnt[((tid << 3) + xcd) << 4], c0);  // 64B-padded
        }
        __syncthreads();
        for (int s = 0; s < 8; s++)
            if (vid[s] >= 0)
                srt[boff[vid[s] >> 6] + vrk[s]] =
                    make_float4(vx[s], vy[s], vz[s], __int_as_float(vid[s]));
        __syncthreads();
        int tot = n - (t << 11);
        tot = tot > 2048 ? 2048 : tot;
        for (int i = tid; i < tot; i += 256) {
            float4 d = srt[i];
            int id = __float_as_int(d.w);
            int b = id >> 6;
            int ofs = bglob[b] + (i - boff[b]);
            int sub = (b << 3) + xcd;
            if (ofs < CAP1) {
                P1[(size_t)sub * CAP1 + ofs] = d;   // coalesced runs (~32)
            } else {
                int ovi = atomicAdd(novf, 1);
                if (ovi < OVCAP) ov[ovi] = d;
                atomicAdd(&gmom[0 * NC + id], 1.0f);
                atomicAdd(&gmom[1 * NC + id], d.x);
                atomicAdd(&gmom[2 * NC + id], d.y);
                atomicAdd(&gmom[3 * NC + id], d.z);
                atomicAdd(&gmom[4 * NC + id], d.x * d.x);
                atomicAdd(&gmom[5 * NC + id], d.x * d.y);
                atomicAdd(&gmom[6 * NC + id], d.x * d.z);
                atomicAdd(&gmom[7 * NC + id], d.y * d.y);
                atomicAdd(&gmom[8 * NC + id], d.y * d.z);
                atomicAdd(&gmom[9 * NC + id], d.z * d.z);
            }
        }
        __syncthreads();
    }
}

// k_mom: per-(sub,slice) block — LDS sort by cluster-in-bucket, per-wave ranged
// shuffle reductions, flush plain partials (NO global atomics).
__global__ __launch_bounds__(256) void k_mom(const float4* __restrict__ P1,
                                             const int* __restrict__ cnt,
                                             float* __restrict__ PM) {
    __shared__ float4 srt[2048];
    __shared__ int h64[64], boff[64];
    __shared__ float acc[64][10];
    int tid = threadIdx.x, w = tid >> 6, lane = tid & 63;
    int sub = blockIdx.x / SL, sl = blockIdx.x % SL;
    int m = cnt[sub << 4];
    m = m > CAP1 ? CAP1 : m;
    int start = (int)((long long)m * sl / SL);
    int end   = (int)((long long)m * (sl + 1) / SL);
    size_t base = (size_t)sub * CAP1;
    for (int e = tid; e < 640; e += 256) acc[e / 10][e % 10] = 0.0f;
    __syncthreads();

    float4 vd[8]; int vrk[8], vcid[8];
    for (int tb = start; tb < end; tb += 2048) {
        if (tid < 64) h64[tid] = 0;
        __syncthreads();
        for (int s = 0; s < 8; s++) {
            int i = tb + (s << 8) + tid;
            if (i < end) {
                float4 d = P1[base + i];
                int cid = __float_as_int(d.w) & 63;
                vd[s] = d; vcid[s] = cid;
                vrk[s] = atomicAdd(&h64[cid], 1);
            } else vcid[s] = -1;
        }
        __syncthreads();
        if (tid < 64) {
            int c0 = h64[tid], sc = c0;
            for (int off = 1; off < 64; off <<= 1) {
                int u = __shfl_up(sc, off);
                if (lane >= off) sc += u;
            }
            boff[tid] = sc - c0;
        }
        __syncthreads();
        for (int s = 0; s < 8; s++)
            if (vcid[s] >= 0) srt[boff[vcid[s]] + vrk[s]] = vd[s];
        __syncthreads();
        for (int k = 0; k < 16; k++) {
            int c = (w << 4) + k;
            int s0 = boff[c], cn = h64[c];
            float m0 = 0, m1 = 0, m2 = 0, m3 = 0, m4 = 0,
                  m5 = 0, m6 = 0, m7 = 0, m8 = 0, m9 = 0;
            for (int j = lane; j < cn; j += 64) {
                float4 d = srt[s0 + j];
                m0 += 1.0f; m1 += d.x; m2 += d.y; m3 += d.z;
                m4 += d.x * d.x; m5 += d.x * d.y; m6 += d.x * d.z;
                m7 += d.y * d.y; m8 += d.y * d.z; m9 += d.z * d.z;
            }
#pragma unroll
            for (int off = 32; off > 0; off >>= 1) {
                m0 += __shfl_down(m0, off); m1 += __shfl_down(m1, off);
                m2 += __shfl_down(m2, off); m3 += __shfl_down(m3, off);
                m4 += __shfl_down(m4, off); m5 += __shfl_down(m5, off);
                m6 += __shfl_down(m6, off); m7 += __shfl_down(m7, off);
                m8 += __shfl_down(m8, off); m9 += __shfl_down(m9, off);
            }
            if (lane == 0) {
                acc[c][0] += m0; acc[c][1] += m1; acc[c][2] += m2; acc[c][3] += m3;
                acc[c][4] += m4; acc[c][5] += m5; acc[c][6] += m6; acc[c][7] += m7;
                acc[c][8] += m8; acc[c][9] += m9;
            }
        }
        __syncthreads();
    }
    size_t row = (size_t)blockIdx.x * 640;
    for (int e = tid; e < 640; e += 256) PM[row + e] = acc[e / 10][e % 10];
}

// k_eigen2: sum partials + eigensolve, write out/pc/pv
__global__ void k_eigen2(const float* __restrict__ PM, const float* __restrict__ gmom,
                         float* __restrict__ out,
                         float4* __restrict__ pc, float4* __restrict__ pv) {
    int c = blockIdx.x * blockDim.x + threadIdx.x;
    if (c >= NC) return;
    int bucket = c >> 6, cid = c & 63;
    float mom[10];
#pragma unroll
    for (int k = 0; k < 10; k++) mom[k] = gmom[k * NC + c];
    for (int x = 0; x < 8; x++)
        for (int sl = 0; sl < SL; sl++) {
            int row = (((bucket << 3) + x) * SL + sl);
            const float* pr = PM + (size_t)row * 640 + cid * 10;
#pragma unroll
            for (int k = 0; k < 10; k++) mom[k] += pr[k];
        }
    solve_cluster(mom, out + c * 16, &pc[c], &pv[c]);
}

// k_sc3: same sort skeleton, per-cluster ranged sc reduction -> PS partials
__global__ __launch_bounds__(256) void k_sc3(const float4* __restrict__ P1,
                                             const int* __restrict__ cnt,
                                             const float4* __restrict__ pc,
                                             const float4* __restrict__ pv,
                                             float* __restrict__ PS) {
    __shared__ float4 srt[2048];
    __shared__ int h64[64], boff[64];
    __shared__ float accs[64];
    int tid = threadIdx.x, w = tid >> 6, lane = tid & 63;
    int sub = blockIdx.x / SL, sl = blockIdx.x % SL;
    int bucket = sub >> 3;
    int m = cnt[sub << 4];
    m = m > CAP1 ? CAP1 : m;
    int start = (int)((long long)m * sl / SL);
    int end   = (int)((long long)m * (sl + 1) / SL);
    size_t base = (size_t)sub * CAP1;
    if (tid < 64) accs[tid] = 0.0f;
    __syncthreads();

    float4 vd[8]; int vrk[8], vcid[8];
    for (int tb = start; tb < end; tb += 2048) {
        if (tid < 64) h64[tid] = 0;
        __syncthreads();
        for (int s = 0; s < 8; s++) {
            int i = tb + (s << 8) + tid;
            if (i < end) {
                float4 d = P1[base + i];
                int cid = __float_as_int(d.w) & 63;
                vd[s] = d; vcid[s] = cid;
                vrk[s] = atomicAdd(&h64[cid], 1);
            } else vcid[s] = -1;
        }
        __syncthreads();
        if (tid < 64) {
            int c0 = h64[tid], sc = c0;
            for (int off = 1; off < 64; off <<= 1) {
                int u = __shfl_up(sc, off);
                if (lane >= off) sc += u;
            }
            boff[tid] = sc - c0;
        }
        __syncthreads();
        for (int s = 0; s < 8; s++)
            if (vcid[s] >= 0) srt[boff[vcid[s]] + vrk[s]] = vd[s];
        __syncthreads();
        for (int k = 0; k < 16; k++) {
            int c = (w << 4) + k;
            int s0 = boff[c], cn = h64[c];
            float4 c4 = pc[bucket * 64 + c];
            float4 v4 = pv[bucket * 64 + c];
            float sa = 0.0f;
            for (int j = lane; j < cn; j += 64) {
                float4 d = srt[s0 + j];
                float xc = d.x - c4.x, yc = d.y - c4.y, zc = d.z - c4.z;
                float x0 = xc * v4.x + yc * v4.y + zc * v4.z;
                float px = xc - x0 * v4.x;
                float py = yc - x0 * v4.y;
                float pz = zc - x0 * v4.z;
                sa += x0 * sqrtf(px * px + py * py + pz * pz);
            }
#pragma unroll
            for (int off = 32; off > 0; off >>= 1) sa += __shfl_down(sa, off);
            if (lane == 0) accs[c] += sa;
        }
        __syncthreads();
    }
    size_t row = (size_t)blockIdx.x * 64;
    if (tid < 64) PS[row + tid] = accs[tid];
}

// k_fin: sum sc partials + rare overflow, finalize v0
__global__ void k_fin(const float* __restrict__ PS,
                      const float4* __restrict__ pc, const float4* __restrict__ pv,
                      const float4* __restrict__ ov, const int* __restrict__ novf,
                      float* __restrict__ out) {
    int c = blockIdx.x * blockDim.x + threadIdx.x;
    if (c >= NC) return;
    int bucket = c >> 6, cid = c & 63;
    float4 c4 = pc[c];
    float4 v4 = pv[c];
    float tot = 0.0f;
    for (int x = 0; x < 8; x++)
        for (int sl = 0; sl < SL; sl++) {
            int row = (((bucket << 3) + x) * SL + sl);
            tot += PS[(size_t)row * 64 + cid];
        }
    int m = *novf;
    m = m > OVCAP ? OVCAP : m;
    for (int i = 0; i < m; i++) {
        float4 d = ov[i];
        if (__float_as_int(d.w) == c) {
            float xc = d.x - c4.x, yc = d.y - c4.y, zc = d.z - c4.z;
            float x0 = xc * v4.x + yc * v4.y + zc * v4.z;
            float px = xc - x0 * v4.x;
            float py = yc - x0 * v4.y;
            float pz = zc - x0 * v4.z;
            tot += x0 * sqrtf(px * px + py * py + pz * pz);
        }
    }
    float s = (tot < 0.0f) ? -c4.w : c4.w;
    if (v4.w < 2.0f) s = 0.0f;
    out[c * 16 + 12] = v4.x * s;
    out[c * 16 + 13] = v4.y * s;
    out[c * 16 + 14] = v4.z * s;
}

// ============================ FALLBACK (r1 structure) ============================
__global__ __launch_bounds__(1024) void k_accum_raw(const float* __restrict__ data,
                                                    const int* __restrict__ ids,
                                                    float* __restrict__ gmom, int n) {
    extern __shared__ float s[];
    for (int i = threadIdx.x; i < 10 * NC; i += blockDim.x) s[i] = 0.0f;
    __syncthreads();
    int stride = gridDim.x * blockDim.x;
    for (int i = blockIdx.x * blockDim.x + threadIdx.x; i < n; i += stride) {
        int id = ids[i];
        float x = data[i * 5 + 0], y = data[i * 5 + 1], z = data[i * 5 + 2];
        atomicAdd(&s[0 * NC + id], 1.0f);
        atomicAdd(&s[1 * NC + id], x);
        atomicAdd(&s[2 * NC + id], y);
        atomicAdd(&s[3 * NC + id], z);
        atomicAdd(&s[4 * NC + id], x * x);
        atomicAdd(&s[5 * NC + id], x * y);
        atomicAdd(&s[6 * NC + id], x * z);
        atomicAdd(&s[7 * NC + id], y * y);
        atomicAdd(&s[8 * NC + id], y * z);
        atomicAdd(&s[9 * NC + id], z * z);
    }
    __syncthreads();
    for (int i = threadIdx.x; i < 10 * NC; i += blockDim.x) {
        float v = s[i];
        if (v != 0.0f) atomicAdd(&gmom[i], v);
    }
}

__global__ void k_eigen_fb(const float* __restrict__ gmom, float* __restrict__ out,
                           float4* __restrict__ pc, float4* __restrict__ pv) {
    int c = blockIdx.x * blockDim.x + threadIdx.x;
    if (c >= NC) return;
    float mom[10];
#pragma unroll
    for (int k = 0; k < 10; k++) mom[k] = gmom[k * NC + c];
    solve_cluster(mom, out + c * 16, &pc[c], &pv[c]);
}

__global__ __launch_bounds__(1024) void k_sc_raw(const float* __restrict__ data,
                                                 const int* __restrict__ ids,
                                                 const float4* __restrict__ pc,
                                                 const float4* __restrict__ pv,
                                                 float* __restrict__ gsc, int n) {
    extern __shared__ float4 sl4[];
    float4* spc = sl4;
    float4* spv = sl4 + NC;
    float*  ssc = (float*)(sl4 + 2 * NC);
    for (int i = threadIdx.x; i < NC; i += blockDim.x) {
        spc[i] = pc[i]; spv[i] = pv[i]; ssc[i] = 0.0f;
    }
    __syncthreads();
    int stride = gridDim.x * blockDim.x;
    for (int i = blockIdx.x * blockDim.x + threadIdx.x; i < n; i += stride) {
        int id = ids[i];
        float4 c4 = spc[id];
        float4 v4 = spv[id];
        float xc = data[i * 5 + 0] - c4.x;
        float yc = data[i * 5 + 1] - c4.y;
        float zc = data[i * 5 + 2] - c4.z;
        float x0 = xc * v4.x + yc * v4.y + zc * v4.z;
        float px = xc - x0 * v4.x;
        float py = yc - x0 * v4.y;
        float pz = zc - x0 * v4.z;
        atomicAdd(&ssc[id], x0 * sqrtf(px * px + py * py + pz * pz));
    }
    __syncthreads();
    for (int i = threadIdx.x; i < NC; i += blockDim.x) {
        float v = ssc[i];
        if (v != 0.0f) atomicAdd(&gsc[i], v);
    }
}

__global__ void k_final_fb(const float4* __restrict__ pc, const float4* __restrict__ pv,
                           const float* __restrict__ gsc, float* __restrict__ out) {
    int c = blockIdx.x * blockDim.x + threadIdx.x;
    if (c >= NC) return;
    float4 c4 = pc[c];
    float4 v4 = pv[c];
    float s = (gsc[c] < 0.0f) ? -c4.w : c4.w;
    if (v4.w < 2.0f) s = 0.0f;
    out[c * 16 + 12] = v4.x * s;
    out[c * 16 + 13] = v4.y * s;
    out[c * 16 + 14] = v4.z * s;
}

// =================================================================================
extern "C" void kernel_launch(void* const* d_in, const int* in_sizes, int n_in,
                              void* d_out, int out_size, void* d_ws, size_t ws_size,
                              hipStream_t stream) {
    const float* data = (const float*)d_in[0];
    const int*   ids  = (const int*)d_in[1];
    float* out = (float*)d_out;
    int n = in_sizes[1];

    char* ws = (char*)d_ws;
    // layout (bytes):
    //   gmom : 40960 f     @ 0         (163840)
    //   cnt  : 512*16 i    @ 163840    (32768)    [64B-padded counters]
    //   novf : 1 i         @ 196608    (pad -> 196672)
    //   pc   : 4096 f4     @ 196672    (65536)
    //   pv   : 4096 f4     @ 262208    (65536)
    //   PM   : 1024*640 f  @ 327744    (2621440)  [also fallback gsc region]
    //   PS   : 1024*64 f   @ 2949184   (262144)
    //   ov   : 131072 f4   @ 3211328   (2097152)
    //   P1   : 512*CAP1 f4 @ 5308480   (93585408)
    float*  gmom = (float*)(ws);
    int*    cnt  = (int*)(ws + 163840);
    int*    novf = (int*)(ws + 196608);
    float4* pc   = (float4*)(ws + 196672);
    float4* pv   = (float4*)(ws + 262208);
    float*  PM   = (float*)(ws + 327744);
    float*  PS   = (float*)(ws + 2949184);
    float4* ov   = (float4*)(ws + 3211328);
    float4* P1   = (float4*)(ws + 5308480);
    size_t need = 5308480 + (size_t)512 * CAP1 * 16;  // = 98,893,888 (proven <= ws r7)

    if (ws_size >= need) {
        hipMemsetAsync(ws, 0, 196672, stream);  // gmom + cnt + novf
        hipLaunchKernelGGL(k_part, dim3(1024), dim3(256), 0, stream,
                           data, ids, P1, cnt, ov, novf, gmom, n);
        hipLaunchKernelGGL(k_mom, dim3(512 * SL), dim3(256), 0, stream,
                           P1, cnt, PM);
        hipLaunchKernelGGL(k_eigen2, dim3(16), dim3(256), 0, stream,
                           PM, gmom, out, pc, pv);
        hipLaunchKernelGGL(k_sc3, dim3(512 * SL), dim3(256), 0, stream,
                           P1, cnt, pc, pv, PS);
        hipLaunchKernelGGL(k_fin, dim3(16), dim3(256), 0, stream,
                           PS, pc, pv, ov, novf, out);
    } else {
        float* gsc = PM;  // reuse region
        hipMemsetAsync(ws, 0, 163840, stream);           // gmom
        hipMemsetAsync(gsc, 0, NC * 4, stream);          // gsc
        hipLaunchKernelGGL(k_accum_raw, dim3(256), dim3(1024), 10 * NC * 4, stream,
                           data, ids, gmom, n);
        hipLaunchKernelGGL(k_eigen_fb, dim3(16), dim3(256), 0, stream, gmom, out, pc, pv);
        hipLaunchKernelGGL(k_sc_raw, dim3(256), dim3(1024), 2 * NC * 16 + NC * 4, stream,
                           data, ids, pc, pv, gsc, n);
        hipLaunchKernelGGL(k_final_fb, dim3(16), dim3(256), 0, stream, pc, pv, gsc, out);
    }
}

// Round 10
// 284.699 us; speedup vs baseline: 7.4562x; 1.4208x over previous
//
#include <hip/hip_runtime.h>
#include <math.h>

#define NC 4096
#define OVCAP 131072
#define CAP1 8520      // per (bucket,xcd) sub-bin: mean 7813 + 8 sigma
#define CAP2 1136      // per cluster: mean 977 + 5 sigma

// Real XCD id: s_getreg(HW_REG_XCC_ID=20, offset 0, size 4) [verified r6]
__device__ __forceinline__ int xcd_id() {
    return (int)__builtin_amdgcn_s_getreg(20 | (0 << 6) | ((4 - 1) << 11));
}

// ---------------- shared per-cluster eigensolve --------------------------------
__device__ __forceinline__ void solve_cluster(const float mom[10], float* o,
                                              float4* pcv, float4* pvv) {
    float cntf = mom[0];
    double dn  = (double)cntf;
    double inv = 1.0 / fmax(dn, 1.0);
    double cx = mom[1] * inv, cy = mom[2] * inv, cz = mom[3] * inv;

    double a00 = (double)mom[4] - dn * cx * cx;
    double a01 = (double)mom[5] - dn * cx * cy;
    double a02 = (double)mom[6] - dn * cx * cz;
    double a11 = (double)mom[7] - dn * cy * cy;
    double a12 = (double)mom[8] - dn * cy * cz;
    double a22 = (double)mom[9] - dn * cz * cz;

    double q  = (a00 + a11 + a22) / 3.0;
    double p1 = a01 * a01 + a02 * a02 + a12 * a12;
    double b00 = a00 - q, b11 = a11 - q, b22 = a22 - q;
    double p2 = b00 * b00 + b11 * b11 + b22 * b22 + 2.0 * p1;
    double w0, w1, w2;
    if (!(p2 > 0.0)) {
        w0 = w1 = w2 = q;
    } else {
        double p  = sqrt(p2 / 6.0);
        double ip = 1.0 / p;
        double c00 = b00 * ip, c01 = a01 * ip, c02 = a02 * ip;
        double c11 = b11 * ip, c12 = a12 * ip, c22 = b22 * ip;
        double detB = c00 * (c11 * c22 - c12 * c12)
                    - c01 * (c01 * c22 - c12 * c02)
                    + c02 * (c01 * c12 - c11 * c02);
        double r = fmin(1.0, fmax(-1.0, detB * 0.5));
        double phi = acos(r) / 3.0;
        w2 = q + 2.0 * p * cos(phi);
        w0 = q + 2.0 * p * cos(phi + 2.0943951023931953);
        w1 = 3.0 * q - w2 - w0;
    }

    double denom = (w2 == 0.0) ? 1.0 : w2;
    double dirwt = (w2 == 0.0) ? 0.0 : (1.0 - w1 / w2);

    double C00 = a00 - w1, C11 = a11 - w1, C22 = a22 - w1;
    double D00 = a00 - w0, D11 = a11 - w0, D22 = a22 - w0;
    double M00 = C00 * D00 + a01 * a01 + a02 * a02;
    double M10 = a01 * D00 + C11 * a01 + a12 * a02;
    double M20 = a02 * D00 + a12 * a01 + C22 * a02;
    double M01 = C00 * a01 + a01 * D11 + a02 * a12;
    double M11 = a01 * a01 + C11 * D11 + a12 * a12;
    double M21 = a02 * a01 + a12 * D11 + C22 * a12;
    double M02 = C00 * a02 + a01 * a12 + a02 * D22;
    double M12 = a01 * a02 + C11 * a12 + a12 * D22;
    double M22 = a02 * a02 + a12 * a12 + C22 * D22;
    double n0 = M00 * M00 + M10 * M10 + M20 * M20;
    double n1 = M01 * M01 + M11 * M11 + M21 * M21;
    double n2 = M02 * M02 + M12 * M12 + M22 * M22;
    double vx, vy, vz, nn;
    if (n0 >= n1 && n0 >= n2) { vx = M00; vy = M10; vz = M20; nn = n0; }
    else if (n1 >= n2)        { vx = M01; vy = M11; vz = M21; nn = n1; }
    else                      { vx = M02; vy = M12; vz = M22; nn = n2; }
    if (nn > 1e-300) {
        double rn = 1.0 / sqrt(nn);
        vx *= rn; vy *= rn; vz *= rn;
    } else {
        vx = vy = vz = 0.0;
    }

    bool small = cntf < 2.0f;
    float bscale = small ? 0.0f : (float)(1.0 / denom);

    o[0]  = (float)cx;
    o[1]  = (float)cy;
    o[2]  = (float)cz;
    o[3]  = (float)a00 * bscale;
    o[4]  = (float)a01 * bscale;
    o[5]  = (float)a02 * bscale;
    o[6]  = (float)a01 * bscale;
    o[7]  = (float)a11 * bscale;
    o[8]  = (float)a12 * bscale;
    o[9]  = (float)a02 * bscale;
    o[10] = (float)a12 * bscale;
    o[11] = (float)a22 * bscale;
    o[15] = cntf;

    *pcv = make_float4((float)cx, (float)cy, (float)cz, (float)dirwt);
    *pvv = make_float4((float)vx, (float)vy, (float)vz, cntf);
}

__device__ __forceinline__ void ov_spill(float4 d, int id, float4* ov, int* novf,
                                         float* gmom) {
    int ovi = atomicAdd(novf, 1);
    if (ovi < OVCAP) ov[ovi] = d;
    atomicAdd(&gmom[0 * NC + id], 1.0f);
    atomicAdd(&gmom[1 * NC + id], d.x);
    atomicAdd(&gmom[2 * NC + id], d.y);
    atomicAdd(&gmom[3 * NC + id], d.z);
    atomicAdd(&gmom[4 * NC + id], d.x * d.x);
    atomicAdd(&gmom[5 * NC + id], d.x * d.y);
    atomicAdd(&gmom[6 * NC + id], d.x * d.z);
    atomicAdd(&gmom[7 * NC + id], d.y * d.y);
    atomicAdd(&gmom[8 * NC + id], d.y * d.z);
    atomicAdd(&gmom[9 * NC + id], d.z * d.z);
}

// ============================ FAST PATH ==========================================
// k_p1: radix pass 1 — voxels -> 64 buckets x 8 XCD shards, block-local LDS sort,
// coalesced run writes (runs ~32 float4). 1 LDS rank-atomic/voxel; 64 padded
// global reservation atomics per 2048-tile.
__global__ __launch_bounds__(256) void k_p1(const float* __restrict__ data,
                                            const int* __restrict__ ids,
                                            float4* __restrict__ P1,
                                            int* __restrict__ cnt1,
                                            float4* __restrict__ ov,
                                            int* __restrict__ novf,
                                            float* __restrict__ gmom, int n) {
    __shared__ float4 srt[2048];
    __shared__ int h64[64], boff[64], bglob[64];
    int tid = threadIdx.x, lane = tid & 63;
    int xcd = xcd_id() & 7;
    int ntiles = (n + 2047) >> 11;
    for (int t = blockIdx.x; t < ntiles; t += gridDim.x) {
        int vbase = t << 11;
        if (tid < 64) h64[tid] = 0;
        __syncthreads();
        float vx[8], vy[8], vz[8];
        int vid[8], vrk[8];
#pragma unroll
        for (int s = 0; s < 8; s++) {
            int v = vbase + (s << 8) + tid;
            if (v < n) {
                vx[s] = data[v * 5 + 0];
                vy[s] = data[v * 5 + 1];
                vz[s] = data[v * 5 + 2];
                int id = ids[v];
                vid[s] = id;
                vrk[s] = atomicAdd(&h64[id >> 6], 1);
            } else vid[s] = -1;
        }
        __syncthreads();
        if (tid < 64) {
            int c0 = h64[tid], sc = c0;
            for (int off = 1; off < 64; off <<= 1) {
                int u = __shfl_up(sc, off);
                if (lane >= off) sc += u;
            }
            boff[tid] = sc - c0;
            bglob[tid] = atomicAdd(&cnt1[((tid << 3) + xcd) << 4], c0);
        }
        __syncthreads();
#pragma unroll
        for (int s = 0; s < 8; s++)
            if (vid[s] >= 0)
                srt[boff[vid[s] >> 6] + vrk[s]] =
                    make_float4(vx[s], vy[s], vz[s], __int_as_float(vid[s]));
        __syncthreads();
        int tot = n - vbase;
        tot = tot > 2048 ? 2048 : tot;
        for (int i = tid; i < tot; i += 256) {
            float4 d = srt[i];
            int id = __float_as_int(d.w);
            int b = id >> 6;
            int ofs = bglob[b] + (i - boff[b]);
            if (ofs < CAP1)
                P1[(size_t)((b << 3) + xcd) * CAP1 + ofs] = d;
            else
                ov_spill(d, id, ov, novf, gmom);
        }
        __syncthreads();
    }
}

// k_p2: radix pass 2 — one bucket-chunk: sub-bin -> fully cluster-sorted P2.
// grid = nb*8*4 (sub-bins x 4 slices).
__global__ __launch_bounds__(256) void k_p2(const float4* __restrict__ P1,
                                            const int* __restrict__ cnt1,
                                            float4* __restrict__ P2,
                                            int* __restrict__ cnt2,
                                            float4* __restrict__ ov,
                                            int* __restrict__ novf,
                                            float* __restrict__ gmom, int b0) {
    __shared__ float4 srt[2048];
    __shared__ int h64[64], boff[64], bglob[64];
    int tid = threadIdx.x, lane = tid & 63;
    int subrel = blockIdx.x >> 2;
    int q = blockIdx.x & 3;
    int b = b0 + (subrel >> 3);
    int sub = (b << 3) + (subrel & 7);
    int m1 = cnt1[sub << 4];
    m1 = m1 > CAP1 ? CAP1 : m1;
    int start = (int)(((long long)m1 * q) >> 2);
    int end   = (int)(((long long)m1 * (q + 1)) >> 2);
    size_t sbase = (size_t)sub * CAP1;

    for (int tb = start; tb < end; tb += 2048) {
        if (tid < 64) h64[tid] = 0;
        __syncthreads();
        float4 vd[8];
        int vrk[8], vcid[8];
#pragma unroll
        for (int s = 0; s < 8; s++) {
            int i = tb + (s << 8) + tid;
            if (i < end) {
                float4 d = P1[sbase + i];
                int cid = __float_as_int(d.w) & 63;
                vd[s] = d; vcid[s] = cid;
                vrk[s] = atomicAdd(&h64[cid], 1);
            } else vcid[s] = -1;
        }
        __syncthreads();
        if (tid < 64) {
            int c0 = h64[tid], sc = c0;
            for (int off = 1; off < 64; off <<= 1) {
                int u = __shfl_up(sc, off);
                if (lane >= off) sc += u;
            }
            boff[tid] = sc - c0;
            bglob[tid] = atomicAdd(&cnt2[((b << 6) + tid) << 4], c0);
        }
        __syncthreads();
#pragma unroll
        for (int s = 0; s < 8; s++)
            if (vcid[s] >= 0) srt[boff[vcid[s]] + vrk[s]] = vd[s];
        __syncthreads();
        int tot = end - tb;
        tot = tot > 2048 ? 2048 : tot;
        for (int i = tid; i < tot; i += 256) {
            float4 d = srt[i];
            int id = __float_as_int(d.w);
            int cid = id & 63;
            int ofs = bglob[cid] + (i - boff[cid]);
            if (ofs < CAP2)
                P2[(size_t)(((b - b0) << 6) + cid) * CAP2 + ofs] = d;
            else
                ov_spill(d, id, ov, novf, gmom);
        }
        __syncthreads();
    }
}

// k_mom: block per cluster — linear coalesced scan of P2 run, register moments,
// ONE block reduction, inline eigensolve.
__global__ __launch_bounds__(256) void k_mom(const float4* __restrict__ P2,
                                             const int* __restrict__ cnt2,
                                             const float* __restrict__ gmom,
                                             float* __restrict__ out,
                                             float4* __restrict__ pc,
                                             float4* __restrict__ pv, int c0) {
    __shared__ float red[4][10];
    int c = c0 + blockIdx.x;
    int tid = threadIdx.x, w = tid >> 6, lane = tid & 63;
    int m = cnt2[c << 4];
    m = m > CAP2 ? CAP2 : m;
    size_t base = (size_t)blockIdx.x * CAP2;
    float a0 = 0, a1 = 0, a2 = 0, a3 = 0, a4 = 0,
          a5 = 0, a6 = 0, a7 = 0, a8 = 0, a9 = 0;
    for (int i = tid; i < m; i += 256) {
        float4 d = P2[base + i];
        a0 += 1.0f;
        a1 += d.x; a2 += d.y; a3 += d.z;
        a4 += d.x * d.x; a5 += d.x * d.y; a6 += d.x * d.z;
        a7 += d.y * d.y; a8 += d.y * d.z; a9 += d.z * d.z;
    }
    float acc[10] = {a0, a1, a2, a3, a4, a5, a6, a7, a8, a9};
#pragma unroll
    for (int k = 0; k < 10; k++) {
        float v = acc[k];
        for (int off = 32; off > 0; off >>= 1) v += __shfl_down(v, off);
        if (lane == 0) red[w][k] = v;
    }
    __syncthreads();
    if (tid == 0) {
        float mom[10];
#pragma unroll
        for (int k = 0; k < 10; k++)
            mom[k] = red[0][k] + red[1][k] + red[2][k] + red[3][k] + gmom[k * NC + c];
        solve_cluster(mom, out + c * 16, &pc[c], &pv[c]);
    }
}

// k_sc: block per cluster — linear scan, sc sum, plain write (single writer).
__global__ __launch_bounds__(256) void k_sc(const float4* __restrict__ P2,
                                            const int* __restrict__ cnt2,
                                            const float4* __restrict__ pc,
                                            const float4* __restrict__ pv,
                                            float* __restrict__ gsc, int c0) {
    __shared__ float red[4];
    int c = c0 + blockIdx.x;
    int tid = threadIdx.x, w = tid >> 6, lane = tid & 63;
    int m = cnt2[c << 4];
    m = m > CAP2 ? CAP2 : m;
    size_t base = (size_t)blockIdx.x * CAP2;
    float4 c4 = pc[c];
    float4 v4 = pv[c];
    float sa = 0.0f;
    for (int i = tid; i < m; i += 256) {
        float4 d = P2[base + i];
        float xc = d.x - c4.x, yc = d.y - c4.y, zc = d.z - c4.z;
        float x0 = xc * v4.x + yc * v4.y + zc * v4.z;
        float px = xc - x0 * v4.x;
        float py = yc - x0 * v4.y;
        float pz = zc - x0 * v4.z;
        sa += x0 * sqrtf(px * px + py * py + pz * pz);
    }
    for (int off = 32; off > 0; off >>= 1) sa += __shfl_down(sa, off);
    if (lane == 0) red[w] = sa;
    __syncthreads();
    if (tid == 0) gsc[c] = red[0] + red[1] + red[2] + red[3];
}

// k_fin: add rare overflow sc + finalize v0
__global__ void k_fin(const float* __restrict__ gsc,
                      const float4* __restrict__ pc, const float4* __restrict__ pv,
                      const float4* __restrict__ ov, const int* __restrict__ novf,
                      float* __restrict__ out) {
    int c = blockIdx.x * blockDim.x + threadIdx.x;
    if (c >= NC) return;
    float4 c4 = pc[c];
    float4 v4 = pv[c];
    float tot = gsc[c];
    int m = *novf;
    m = m > OVCAP ? OVCAP : m;
    for (int i = 0; i < m; i++) {
        float4 d = ov[i];
        if (__float_as_int(d.w) == c) {
            float xc = d.x - c4.x, yc = d.y - c4.y, zc = d.z - c4.z;
            float x0 = xc * v4.x + yc * v4.y + zc * v4.z;
            float px = xc - x0 * v4.x;
            float py = yc - x0 * v4.y;
            float pz = zc - x0 * v4.z;
            tot += x0 * sqrtf(px * px + py * py + pz * pz);
        }
    }
    float s = (tot < 0.0f) ? -c4.w : c4.w;
    if (v4.w < 2.0f) s = 0.0f;
    out[c * 16 + 12] = v4.x * s;
    out[c * 16 + 13] = v4.y * s;
    out[c * 16 + 14] = v4.z * s;
}

// ============================ FALLBACK (r1 structure) ============================
__global__ __launch_bounds__(1024) void k_accum_raw(const float* __restrict__ data,
                                                    const int* __restrict__ ids,
                                                    float* __restrict__ gmom, int n) {
    extern __shared__ float s[];
    for (int i = threadIdx.x; i < 10 * NC; i += blockDim.x) s[i] = 0.0f;
    __syncthreads();
    int stride = gridDim.x * blockDim.x;
    for (int i = blockIdx.x * blockDim.x + threadIdx.x; i < n; i += stride) {
        int id = ids[i];
        float x = data[i * 5 + 0], y = data[i * 5 + 1], z = data[i * 5 + 2];
        atomicAdd(&s[0 * NC + id], 1.0f);
        atomicAdd(&s[1 * NC + id], x);
        atomicAdd(&s[2 * NC + id], y);
        atomicAdd(&s[3 * NC + id], z);
        atomicAdd(&s[4 * NC + id], x * x);
        atomicAdd(&s[5 * NC + id], x * y);
        atomicAdd(&s[6 * NC + id], x * z);
        atomicAdd(&s[7 * NC + id], y * y);
        atomicAdd(&s[8 * NC + id], y * z);
        atomicAdd(&s[9 * NC + id], z * z);
    }
    __syncthreads();
    for (int i = threadIdx.x; i < 10 * NC; i += blockDim.x) {
        float v = s[i];
        if (v != 0.0f) atomicAdd(&gmom[i], v);
    }
}

__global__ void k_eigen_fb(const float* __restrict__ gmom, float* __restrict__ out,
                           float4* __restrict__ pc, float4* __restrict__ pv) {
    int c = blockIdx.x * blockDim.x + threadIdx.x;
    if (c >= NC) return;
    float mom[10];
#pragma unroll
    for (int k = 0; k < 10; k++) mom[k] = gmom[k * NC + c];
    solve_cluster(mom, out + c * 16, &pc[c], &pv[c]);
}

__global__ __launch_bounds__(1024) void k_sc_raw(const float* __restrict__ data,
                                                 const int* __restrict__ ids,
                                                 const float4* __restrict__ pc,
                                                 const float4* __restrict__ pv,
                                                 float* __restrict__ gsc, int n) {
    extern __shared__ float4 sl4[];
    float4* spc = sl4;
    float4* spv = sl4 + NC;
    float*  ssc = (float*)(sl4 + 2 * NC);
    for (int i = threadIdx.x; i < NC; i += blockDim.x) {
        spc[i] = pc[i]; spv[i] = pv[i]; ssc[i] = 0.0f;
    }
    __syncthreads();
    int stride = gridDim.x * blockDim.x;
    for (int i = blockIdx.x * blockDim.x + threadIdx.x; i < n; i += stride) {
        int id = ids[i];
        float4 c4 = spc[id];
        float4 v4 = spv[id];
        float xc = data[i * 5 + 0] - c4.x;
        float yc = data[i * 5 + 1] - c4.y;
        float zc = data[i * 5 + 2] - c4.z;
        float x0 = xc * v4.x + yc * v4.y + zc * v4.z;
        float px = xc - x0 * v4.x;
        float py = yc - x0 * v4.y;
        float pz = zc - x0 * v4.z;
        atomicAdd(&ssc[id], x0 * sqrtf(px * px + py * py + pz * pz));
    }
    __syncthreads();
    for (int i = threadIdx.x; i < NC; i += blockDim.x) {
        float v = ssc[i];
        if (v != 0.0f) atomicAdd(&gsc[i], v);
    }
}

__global__ void k_final_fb(const float4* __restrict__ pc, const float4* __restrict__ pv,
                           const float* __restrict__ gsc, float* __restrict__ out) {
    int c = blockIdx.x * blockDim.x + threadIdx.x;
    if (c >= NC) return;
    float4 c4 = pc[c];
    float4 v4 = pv[c];
    float s = (gsc[c] < 0.0f) ? -c4.w : c4.w;
    if (v4.w < 2.0f) s = 0.0f;
    out[c * 16 + 12] = v4.x * s;
    out[c * 16 + 13] = v4.y * s;
    out[c * 16 + 14] = v4.z * s;
}

// =================================================================================
extern "C" void kernel_launch(void* const* d_in, const int* in_sizes, int n_in,
                              void* d_out, int out_size, void* d_ws, size_t ws_size,
                              hipStream_t stream) {
    const float* data = (const float*)d_in[0];
    const int*   ids  = (const int*)d_in[1];
    float* out = (float*)d_out;
    int n = in_sizes[1];

    char* ws = (char*)d_ws;
    // layout (bytes):
    //   gmom : 40960 f       @ 0         (163840)
    //   gsc  : 4096 f        @ 163840    (16384)
    //   cnt1 : 512*16 i      @ 180224    (32768)   [64B-padded]
    //   cnt2 : 4096*16 i     @ 212992    (262144)  [64B-padded]
    //   novf : 1 i           @ 475136    (64)
    //   pc   : 4096 f4       @ 475200    (65536)
    //   pv   : 4096 f4       @ 540736    (65536)
    //   ov   : 131072 f4     @ 606272    (2097152)
    //   P2   : 1408*CAP2 f4  @ 2703424   (25591808)  [chunk-reused]
    //   P1   : 512*CAP1 f4   @ 28295232  (69795840)
    // total = 98,091,072  (<= 98,893,888 proven available in r8)
    float*  gmom = (float*)(ws);
    float*  gsc  = (float*)(ws + 163840);
    int*    cnt1 = (int*)(ws + 180224);
    int*    cnt2 = (int*)(ws + 212992);
    int*    novf = (int*)(ws + 475136);
    float4* pc   = (float4*)(ws + 475200);
    float4* pv   = (float4*)(ws + 540736);
    float4* ov   = (float4*)(ws + 606272);
    float4* P2   = (float4*)(ws + 2703424);
    float4* P1   = (float4*)(ws + 28295232);
    const size_t need = 98091072;

    if (ws_size >= need) {
        hipMemsetAsync(ws, 0, 475200, stream);  // gmom+gsc+cnt1+cnt2+novf
        hipLaunchKernelGGL(k_p1, dim3(2048), dim3(256), 0, stream,
                           data, ids, P1, cnt1, ov, novf, gmom, n);
        // chunks of buckets: (b0,nb) = (0,22), (22,22), (44,20)
        const int b0s[3] = {0, 22, 44};
        const int nbs[3] = {22, 22, 20};
        for (int ch = 0; ch < 3; ch++) {
            int b0 = b0s[ch], nb = nbs[ch];
            hipLaunchKernelGGL(k_p2, dim3(nb * 8 * 4), dim3(256), 0, stream,
                               P1, cnt1, P2, cnt2, ov, novf, gmom, b0);
            hipLaunchKernelGGL(k_mom, dim3(nb * 64), dim3(256), 0, stream,
                               P2, cnt2, gmom, out, pc, pv, b0 * 64);
            hipLaunchKernelGGL(k_sc, dim3(nb * 64), dim3(256), 0, stream,
                               P2, cnt2, pc, pv, gsc, b0 * 64);
        }
        hipLaunchKernelGGL(k_fin, dim3(16), dim3(256), 0, stream,
                           gsc, pc, pv, ov, novf, out);
    } else {
        hipMemsetAsync(ws, 0, 180224, stream);  // gmom + gsc
        hipLaunchKernelGGL(k_accum_raw, dim3(256), dim3(1024), 10 * NC * 4, stream,
                           data, ids, gmom, n);
        hipLaunchKernelGGL(k_eigen_fb, dim3(16), dim3(256), 0, stream, gmom, out, pc, pv);
        hipLaunchKernelGGL(k_sc_raw, dim3(256), dim3(1024), 2 * NC * 16 + NC * 4, stream,
                           data, ids, pc, pv, gsc, n);
        hipLaunchKernelGGL(k_final_fb, dim3(16), dim3(256), 0, stream, pc, pv, gsc, out);
    }
}

// Round 11
// 231.331 us; speedup vs baseline: 9.1764x; 1.2307x over previous
//
#include <hip/hip_runtime.h>
#include <math.h>

#define NC 4096
#define OVCAP 131072
#define CAP1 8520      // per (bucket,xcd) sub-bin: mean 7813 + 8 sigma
#define CAP2 1136      // per cluster: mean 977 + 5 sigma

// Real XCD id: s_getreg(HW_REG_XCC_ID=20, offset 0, size 4) [verified r6]
__device__ __forceinline__ int xcd_id() {
    return (int)__builtin_amdgcn_s_getreg(20 | (0 << 6) | ((4 - 1) << 11));
}

// ---------------- shared per-cluster eigensolve --------------------------------
__device__ __forceinline__ void solve_cluster(const float mom[10], float* o,
                                              float4* pcv, float4* pvv) {
    float cntf = mom[0];
    double dn  = (double)cntf;
    double inv = 1.0 / fmax(dn, 1.0);
    double cx = mom[1] * inv, cy = mom[2] * inv, cz = mom[3] * inv;

    double a00 = (double)mom[4] - dn * cx * cx;
    double a01 = (double)mom[5] - dn * cx * cy;
    double a02 = (double)mom[6] - dn * cx * cz;
    double a11 = (double)mom[7] - dn * cy * cy;
    double a12 = (double)mom[8] - dn * cy * cz;
    double a22 = (double)mom[9] - dn * cz * cz;

    double q  = (a00 + a11 + a22) / 3.0;
    double p1 = a01 * a01 + a02 * a02 + a12 * a12;
    double b00 = a00 - q, b11 = a11 - q, b22 = a22 - q;
    double p2 = b00 * b00 + b11 * b11 + b22 * b22 + 2.0 * p1;
    double w0, w1, w2;
    if (!(p2 > 0.0)) {
        w0 = w1 = w2 = q;
    } else {
        double p  = sqrt(p2 / 6.0);
        double ip = 1.0 / p;
        double c00 = b00 * ip, c01 = a01 * ip, c02 = a02 * ip;
        double c11 = b11 * ip, c12 = a12 * ip, c22 = b22 * ip;
        double detB = c00 * (c11 * c22 - c12 * c12)
                    - c01 * (c01 * c22 - c12 * c02)
                    + c02 * (c01 * c12 - c11 * c02);
        double r = fmin(1.0, fmax(-1.0, detB * 0.5));
        double phi = acos(r) / 3.0;
        w2 = q + 2.0 * p * cos(phi);
        w0 = q + 2.0 * p * cos(phi + 2.0943951023931953);
        w1 = 3.0 * q - w2 - w0;
    }

    double denom = (w2 == 0.0) ? 1.0 : w2;
    double dirwt = (w2 == 0.0) ? 0.0 : (1.0 - w1 / w2);

    double C00 = a00 - w1, C11 = a11 - w1, C22 = a22 - w1;
    double D00 = a00 - w0, D11 = a11 - w0, D22 = a22 - w0;
    double M00 = C00 * D00 + a01 * a01 + a02 * a02;
    double M10 = a01 * D00 + C11 * a01 + a12 * a02;
    double M20 = a02 * D00 + a12 * a01 + C22 * a02;
    double M01 = C00 * a01 + a01 * D11 + a02 * a12;
    double M11 = a01 * a01 + C11 * D11 + a12 * a12;
    double M21 = a02 * a01 + a12 * D11 + C22 * a12;
    double M02 = C00 * a02 + a01 * a12 + a02 * D22;
    double M12 = a01 * a02 + C11 * a12 + a12 * D22;
    double M22 = a02 * a02 + a12 * a12 + C22 * D22;
    double n0 = M00 * M00 + M10 * M10 + M20 * M20;
    double n1 = M01 * M01 + M11 * M11 + M21 * M21;
    double n2 = M02 * M02 + M12 * M12 + M22 * M22;
    double vx, vy, vz, nn;
    if (n0 >= n1 && n0 >= n2) { vx = M00; vy = M10; vz = M20; nn = n0; }
    else if (n1 >= n2)        { vx = M01; vy = M11; vz = M21; nn = n1; }
    else                      { vx = M02; vy = M12; vz = M22; nn = n2; }
    if (nn > 1e-300) {
        double rn = 1.0 / sqrt(nn);
        vx *= rn; vy *= rn; vz *= rn;
    } else {
        vx = vy = vz = 0.0;
    }

    bool small = cntf < 2.0f;
    float bscale = small ? 0.0f : (float)(1.0 / denom);

    o[0]  = (float)cx;
    o[1]  = (float)cy;
    o[2]  = (float)cz;
    o[3]  = (float)a00 * bscale;
    o[4]  = (float)a01 * bscale;
    o[5]  = (float)a02 * bscale;
    o[6]  = (float)a01 * bscale;
    o[7]  = (float)a11 * bscale;
    o[8]  = (float)a12 * bscale;
    o[9]  = (float)a02 * bscale;
    o[10] = (float)a12 * bscale;
    o[11] = (float)a22 * bscale;
    o[15] = cntf;

    *pcv = make_float4((float)cx, (float)cy, (float)cz, (float)dirwt);
    *pvv = make_float4((float)vx, (float)vy, (float)vz, cntf);
}

__device__ __forceinline__ void ov_spill(float4 d, int id, float4* ov, int* novf,
                                         float* gmom) {
    int ovi = atomicAdd(novf, 1);
    if (ovi < OVCAP) ov[ovi] = d;
    atomicAdd(&gmom[0 * NC + id], 1.0f);
    atomicAdd(&gmom[1 * NC + id], d.x);
    atomicAdd(&gmom[2 * NC + id], d.y);
    atomicAdd(&gmom[3 * NC + id], d.z);
    atomicAdd(&gmom[4 * NC + id], d.x * d.x);
    atomicAdd(&gmom[5 * NC + id], d.x * d.y);
    atomicAdd(&gmom[6 * NC + id], d.x * d.z);
    atomicAdd(&gmom[7 * NC + id], d.y * d.y);
    atomicAdd(&gmom[8 * NC + id], d.y * d.z);
    atomicAdd(&gmom[9 * NC + id], d.z * d.z);
}

// ============================ FAST PATH ==========================================
// k_p1: radix pass 1 — voxels -> 64 buckets x 8 XCD shards, block-local LDS sort,
// coalesced run writes. [r10 control: 53 us, WRITE 66.5 MB]
__global__ __launch_bounds__(256) void k_p1(const float* __restrict__ data,
                                            const int* __restrict__ ids,
                                            float4* __restrict__ P1,
                                            int* __restrict__ cnt1,
                                            float4* __restrict__ ov,
                                            int* __restrict__ novf,
                                            float* __restrict__ gmom, int n) {
    __shared__ float4 srt[2048];
    __shared__ int h64[64], boff[64], bglob[64];
    int tid = threadIdx.x, lane = tid & 63;
    int xcd = xcd_id() & 7;
    int ntiles = (n + 2047) >> 11;
    for (int t = blockIdx.x; t < ntiles; t += gridDim.x) {
        int vbase = t << 11;
        if (tid < 64) h64[tid] = 0;
        __syncthreads();
        float vx[8], vy[8], vz[8];
        int vid[8], vrk[8];
#pragma unroll
        for (int s = 0; s < 8; s++) {
            int v = vbase + (s << 8) + tid;
            if (v < n) {
                vx[s] = data[v * 5 + 0];
                vy[s] = data[v * 5 + 1];
                vz[s] = data[v * 5 + 2];
                int id = ids[v];
                vid[s] = id;
                vrk[s] = atomicAdd(&h64[id >> 6], 1);
            } else vid[s] = -1;
        }
        __syncthreads();
        if (tid < 64) {
            int c0 = h64[tid], sc = c0;
            for (int off = 1; off < 64; off <<= 1) {
                int u = __shfl_up(sc, off);
                if (lane >= off) sc += u;
            }
            boff[tid] = sc - c0;
            bglob[tid] = atomicAdd(&cnt1[((tid << 3) + xcd) << 4], c0);
        }
        __syncthreads();
#pragma unroll
        for (int s = 0; s < 8; s++)
            if (vid[s] >= 0)
                srt[boff[vid[s] >> 6] + vrk[s]] =
                    make_float4(vx[s], vy[s], vz[s], __int_as_float(vid[s]));
        __syncthreads();
        int tot = n - vbase;
        tot = tot > 2048 ? 2048 : tot;
        for (int i = tid; i < tot; i += 256) {
            float4 d = srt[i];
            int id = __float_as_int(d.w);
            int b = id >> 6;
            int ofs = bglob[b] + (i - boff[b]);
            if (ofs < CAP1)
                P1[(size_t)((b << 3) + xcd) * CAP1 + ofs] = d;
            else
                ov_spill(d, id, ov, novf, gmom);
        }
        __syncthreads();
    }
}

// k_p2: radix pass 2 — one bucket-chunk: sub-bin -> fully cluster-sorted P2.
// grid = nb*8*4 (sub-bins x 4 slices).
__global__ __launch_bounds__(256) void k_p2(const float4* __restrict__ P1,
                                            const int* __restrict__ cnt1,
                                            float4* __restrict__ P2,
                                            int* __restrict__ cnt2,
                                            float4* __restrict__ ov,
                                            int* __restrict__ novf,
                                            float* __restrict__ gmom, int b0) {
    __shared__ float4 srt[2048];
    __shared__ int h64[64], boff[64], bglob[64];
    int tid = threadIdx.x, lane = tid & 63;
    int subrel = blockIdx.x >> 2;
    int q = blockIdx.x & 3;
    int b = b0 + (subrel >> 3);
    int sub = (b << 3) + (subrel & 7);
    int m1 = cnt1[sub << 4];
    m1 = m1 > CAP1 ? CAP1 : m1;
    int start = (int)(((long long)m1 * q) >> 2);
    int end   = (int)(((long long)m1 * (q + 1)) >> 2);
    size_t sbase = (size_t)sub * CAP1;

    for (int tb = start; tb < end; tb += 2048) {
        if (tid < 64) h64[tid] = 0;
        __syncthreads();
        float4 vd[8];
        int vrk[8], vcid[8];
#pragma unroll
        for (int s = 0; s < 8; s++) {
            int i = tb + (s << 8) + tid;
            if (i < end) {
                float4 d = P1[sbase + i];
                int cid = __float_as_int(d.w) & 63;
                vd[s] = d; vcid[s] = cid;
                vrk[s] = atomicAdd(&h64[cid], 1);
            } else vcid[s] = -1;
        }
        __syncthreads();
        if (tid < 64) {
            int c0 = h64[tid], sc = c0;
            for (int off = 1; off < 64; off <<= 1) {
                int u = __shfl_up(sc, off);
                if (lane >= off) sc += u;
            }
            boff[tid] = sc - c0;
            bglob[tid] = atomicAdd(&cnt2[((b << 6) + tid) << 4], c0);
        }
        __syncthreads();
#pragma unroll
        for (int s = 0; s < 8; s++)
            if (vcid[s] >= 0) srt[boff[vcid[s]] + vrk[s]] = vd[s];
        __syncthreads();
        int tot = end - tb;
        tot = tot > 2048 ? 2048 : tot;
        for (int i = tid; i < tot; i += 256) {
            float4 d = srt[i];
            int id = __float_as_int(d.w);
            int cid = id & 63;
            int ofs = bglob[cid] + (i - boff[cid]);
            if (ofs < CAP2)
                P2[(size_t)(((b - b0) << 6) + cid) * CAP2 + ofs] = d;
            else
                ov_spill(d, id, ov, novf, gmom);
        }
        __syncthreads();
    }
}

// k_msc: block per cluster — moments scan + inline eigensolve + sc scan
// (second scan is L2-hot) + overflow + v0 finalize. Fuses r10's k_mom/k_sc/k_fin.
__global__ __launch_bounds__(256) void k_msc(const float4* __restrict__ P2,
                                             const int* __restrict__ cnt2,
                                             const float* __restrict__ gmom,
                                             const float4* __restrict__ ov,
                                             const int* __restrict__ novf,
                                             float* __restrict__ out, int c0) {
    __shared__ float red[4][10];
    __shared__ float4 sh_c4, sh_v4;
    int c = c0 + blockIdx.x;
    int tid = threadIdx.x, w = tid >> 6, lane = tid & 63;
    int m = cnt2[c << 4];
    m = m > CAP2 ? CAP2 : m;
    size_t base = (size_t)blockIdx.x * CAP2;

    // ---- scan 1: moments ----
    float a0 = 0, a1 = 0, a2 = 0, a3 = 0, a4 = 0,
          a5 = 0, a6 = 0, a7 = 0, a8 = 0, a9 = 0;
    for (int i = tid; i < m; i += 256) {
        float4 d = P2[base + i];
        a0 += 1.0f;
        a1 += d.x; a2 += d.y; a3 += d.z;
        a4 += d.x * d.x; a5 += d.x * d.y; a6 += d.x * d.z;
        a7 += d.y * d.y; a8 += d.y * d.z; a9 += d.z * d.z;
    }
    float acc[10] = {a0, a1, a2, a3, a4, a5, a6, a7, a8, a9};
#pragma unroll
    for (int k = 0; k < 10; k++) {
        float v = acc[k];
        for (int off = 32; off > 0; off >>= 1) v += __shfl_down(v, off);
        if (lane == 0) red[w][k] = v;
    }
    __syncthreads();
    if (tid == 0) {
        float mom[10];
#pragma unroll
        for (int k = 0; k < 10; k++)
            mom[k] = red[0][k] + red[1][k] + red[2][k] + red[3][k] + gmom[k * NC + c];
        float4 pcv, pvv;
        solve_cluster(mom, out + c * 16, &pcv, &pvv);
        sh_c4 = pcv; sh_v4 = pvv;
    }
    __syncthreads();
    float4 c4 = sh_c4;
    float4 v4 = sh_v4;

    // ---- scan 2: sc (data L2-hot) ----
    float sa = 0.0f;
    for (int i = tid; i < m; i += 256) {
        float4 d = P2[base + i];
        float xc = d.x - c4.x, yc = d.y - c4.y, zc = d.z - c4.z;
        float x0 = xc * v4.x + yc * v4.y + zc * v4.z;
        float px = xc - x0 * v4.x;
        float py = yc - x0 * v4.y;
        float pz = zc - x0 * v4.z;
        sa += x0 * sqrtf(px * px + py * py + pz * pz);
    }
    // rare overflow contributions (novf normally 0)
    int mo = *novf;
    mo = mo > OVCAP ? OVCAP : mo;
    for (int i = tid; i < mo; i += 256) {
        float4 d = ov[i];
        if (__float_as_int(d.w) == c) {
            float xc = d.x - c4.x, yc = d.y - c4.y, zc = d.z - c4.z;
            float x0 = xc * v4.x + yc * v4.y + zc * v4.z;
            float px = xc - x0 * v4.x;
            float py = yc - x0 * v4.y;
            float pz = zc - x0 * v4.z;
            sa += x0 * sqrtf(px * px + py * py + pz * pz);
        }
    }
    for (int off = 32; off > 0; off >>= 1) sa += __shfl_down(sa, off);
    if (lane == 0) red[w][0] = sa;
    __syncthreads();
    if (tid == 0) {
        float tot = red[0][0] + red[1][0] + red[2][0] + red[3][0];
        float s = (tot < 0.0f) ? -c4.w : c4.w;
        if (v4.w < 2.0f) s = 0.0f;
        out[c * 16 + 12] = v4.x * s;
        out[c * 16 + 13] = v4.y * s;
        out[c * 16 + 14] = v4.z * s;
    }
}

// ============================ FALLBACK (r1 structure) ============================
__global__ __launch_bounds__(1024) void k_accum_raw(const float* __restrict__ data,
                                                    const int* __restrict__ ids,
                                                    float* __restrict__ gmom, int n) {
    extern __shared__ float s[];
    for (int i = threadIdx.x; i < 10 * NC; i += blockDim.x) s[i] = 0.0f;
    __syncthreads();
    int stride = gridDim.x * blockDim.x;
    for (int i = blockIdx.x * blockDim.x + threadIdx.x; i < n; i += stride) {
        int id = ids[i];
        float x = data[i * 5 + 0], y = data[i * 5 + 1], z = data[i * 5 + 2];
        atomicAdd(&s[0 * NC + id], 1.0f);
        atomicAdd(&s[1 * NC + id], x);
        atomicAdd(&s[2 * NC + id], y);
        atomicAdd(&s[3 * NC + id], z);
        atomicAdd(&s[4 * NC + id], x * x);
        atomicAdd(&s[5 * NC + id], x * y);
        atomicAdd(&s[6 * NC + id], x * z);
        atomicAdd(&s[7 * NC + id], y * y);
        atomicAdd(&s[8 * NC + id], y * z);
        atomicAdd(&s[9 * NC + id], z * z);
    }
    __syncthreads();
    for (int i = threadIdx.x; i < 10 * NC; i += blockDim.x) {
        float v = s[i];
        if (v != 0.0f) atomicAdd(&gmom[i], v);
    }
}

__global__ void k_eigen_fb(const float* __restrict__ gmom, float* __restrict__ out,
                           float4* __restrict__ pc, float4* __restrict__ pv) {
    int c = blockIdx.x * blockDim.x + threadIdx.x;
    if (c >= NC) return;
    float mom[10];
#pragma unroll
    for (int k = 0; k < 10; k++) mom[k] = gmom[k * NC + c];
    solve_cluster(mom, out + c * 16, &pc[c], &pv[c]);
}

__global__ __launch_bounds__(1024) void k_sc_raw(const float* __restrict__ data,
                                                 const int* __restrict__ ids,
                                                 const float4* __restrict__ pc,
                                                 const float4* __restrict__ pv,
                                                 float* __restrict__ gsc, int n) {
    extern __shared__ float4 sl4[];
    float4* spc = sl4;
    float4* spv = sl4 + NC;
    float*  ssc = (float*)(sl4 + 2 * NC);
    for (int i = threadIdx.x; i < NC; i += blockDim.x) {
        spc[i] = pc[i]; spv[i] = pv[i]; ssc[i] = 0.0f;
    }
    __syncthreads();
    int stride = gridDim.x * blockDim.x;
    for (int i = blockIdx.x * blockDim.x + threadIdx.x; i < n; i += stride) {
        int id = ids[i];
        float4 c4 = spc[id];
        float4 v4 = spv[id];
        float xc = data[i * 5 + 0] - c4.x;
        float yc = data[i * 5 + 1] - c4.y;
        float zc = data[i * 5 + 2] - c4.z;
        float x0 = xc * v4.x + yc * v4.y + zc * v4.z;
        float px = xc - x0 * v4.x;
        float py = yc - x0 * v4.y;
        float pz = zc - x0 * v4.z;
        atomicAdd(&ssc[id], x0 * sqrtf(px * px + py * py + pz * pz));
    }
    __syncthreads();
    for (int i = threadIdx.x; i < NC; i += blockDim.x) {
        float v = ssc[i];
        if (v != 0.0f) atomicAdd(&gsc[i], v);
    }
}

__global__ void k_final_fb(const float4* __restrict__ pc, const float4* __restrict__ pv,
                           const float* __restrict__ gsc, float* __restrict__ out) {
    int c = blockIdx.x * blockDim.x + threadIdx.x;
    if (c >= NC) return;
    float4 c4 = pc[c];
    float4 v4 = pv[c];
    float s = (gsc[c] < 0.0f) ? -c4.w : c4.w;
    if (v4.w < 2.0f) s = 0.0f;
    out[c * 16 + 12] = v4.x * s;
    out[c * 16 + 13] = v4.y * s;
    out[c * 16 + 14] = v4.z * s;
}

// =================================================================================
extern "C" void kernel_launch(void* const* d_in, const int* in_sizes, int n_in,
                              void* d_out, int out_size, void* d_ws, size_t ws_size,
                              hipStream_t stream) {
    const float* data = (const float*)d_in[0];
    const int*   ids  = (const int*)d_in[1];
    float* out = (float*)d_out;
    int n = in_sizes[1];

    char* ws = (char*)d_ws;
    // fixed layout (bytes):
    //   gmom : 40960 f    @ 0        (163840)
    //   gsc  : 4096 f     @ 163840   (16384)   [fallback only]
    //   cnt1 : 512*16 i   @ 180224   (32768)   [64B-padded]
    //   cnt2 : 4096*16 i  @ 212992   (262144)  [64B-padded]
    //   novf : 1 i        @ 475136   (64)
    //   pc   : 4096 f4    @ 475200   (65536)   [fallback only]
    //   pv   : 4096 f4    @ 540736   (65536)   [fallback only]
    //   ov   : 131072 f4  @ 606272   (2097152)
    //   P2   : nb*64*CAP2 f4 @ 2703424
    //   P1   : 512*CAP1 f4   @ after P2
    float*  gmom = (float*)(ws);
    float*  gsc  = (float*)(ws + 163840);
    int*    cnt1 = (int*)(ws + 180224);
    int*    cnt2 = (int*)(ws + 212992);
    int*    novf = (int*)(ws + 475136);
    float4* pc   = (float4*)(ws + 475200);
    float4* pv   = (float4*)(ws + 540736);
    float4* ov   = (float4*)(ws + 606272);
    const size_t FIXED = 2703424;
    const size_t P1SZ  = (size_t)512 * CAP1 * 16;   // 69,795,840

    // flexible chunking: nb = buckets per chunk that fit in the P2 region
    int nb = 0;
    if (ws_size > FIXED + P1SZ) {
        size_t avail = ws_size - FIXED - P1SZ;
        size_t clcap = avail / ((size_t)CAP2 * 16);
        size_t nbl = clcap / 64;
        nb = nbl > 64 ? 64 : (int)nbl;
    }
    // proven ws >= 99,008,768 (r4) -> nb = 22 -> 3 chunks, same footprint as r10

    if (nb >= 1) {
        float4* P2 = (float4*)(ws + FIXED);
        float4* P1 = (float4*)(ws + FIXED + (size_t)nb * 64 * CAP2 * 16);

        hipMemsetAsync(ws, 0, 475200, stream);  // gmom+gsc+cnt1+cnt2+novf
        hipLaunchKernelGGL(k_p1, dim3(2048), dim3(256), 0, stream,
                           data, ids, P1, cnt1, ov, novf, gmom, n);
        for (int b0 = 0; b0 < 64; b0 += nb) {
            int nbc = (64 - b0) < nb ? (64 - b0) : nb;
            hipLaunchKernelGGL(k_p2, dim3(nbc * 32), dim3(256), 0, stream,
                               P1, cnt1, P2, cnt2, ov, novf, gmom, b0);
            hipLaunchKernelGGL(k_msc, dim3(nbc * 64), dim3(256), 0, stream,
                               P2, cnt2, gmom, ov, novf, out, b0 * 64);
        }
    } else {
        hipMemsetAsync(ws, 0, 180224, stream);  // gmom + gsc
        hipLaunchKernelGGL(k_accum_raw, dim3(256), dim3(1024), 10 * NC * 4, stream,
                           data, ids, gmom, n);
        hipLaunchKernelGGL(k_eigen_fb, dim3(16), dim3(256), 0, stream, gmom, out, pc, pv);
        hipLaunchKernelGGL(k_sc_raw, dim3(256), dim3(1024), 2 * NC * 16 + NC * 4, stream,
                           data, ids, pc, pv, gsc, n);
        hipLaunchKernelGGL(k_final_fb, dim3(16), dim3(256), 0, stream, pc, pv, gsc, out);
    }
}